// Round 21
// baseline (37.020 us; speedup 1.0000x reference)
//
#include <hip/hip_runtime.h>
#include <hip/hip_bf16.h>

#define D_ 128
#define S_ 512
#define B_ 4
#define H_ 8

typedef short bf16x8 __attribute__((ext_vector_type(8)));
typedef unsigned int u32x4 __attribute__((ext_vector_type(4)));
typedef float f32x4 __attribute__((ext_vector_type(4)));
typedef float f32x2 __attribute__((ext_vector_type(2)));

__device__ __forceinline__ short f2bf(float f) {
  __hip_bfloat16 h = __float2bfloat16(f);
  return __builtin_bit_cast(short, h);
}
// HW packed f32->bf16 (RNE) — verified r9/r14.
__device__ __forceinline__ unsigned int cvt_pk_bf16(float lo, float hi) {
  unsigned int r;
  asm("v_cvt_pk_bf16_f32 %0, %1, %2" : "=v"(r) : "v"(lo), "v"(hi));
  return r;
}

// Proj v2 (r9/r19 verbatim, verified): A (+b1) -> f32 Aq, C -> f32 Cq.
// 512 blocks x 256 thr, k-quarter split; w1 read once per block.
__global__ __launch_bounds__(256)
void proj_kernel(const float* __restrict__ x, const float* __restrict__ w1,
                 const float* __restrict__ b1, float* __restrict__ Aq,
                 float* __restrict__ Cq) {
  __shared__ float xs[4 * D_];
  __shared__ f32x4 red[256][5];
  const int t = threadIdx.x;
  const int row0 = blockIdx.x * 4;
  ((float2*)xs)[t] = ((const float2*)(x + row0 * D_))[t];
  __syncthreads();
  const int combo = t & 63;
  const int e4 = (combo & 31) * 4;
  const int half = combo >> 5;
  const int kq = t >> 6;
  const float* w1p = w1 + (half * D_ + kq * 32) * D_ + e4;
  const float* xq = xs + kq * 32;
  f32x4 acc[4] = {};
  #pragma unroll 8
  for (int k = 0; k < 32; ++k) {
    float4 wv = *(const float4*)(w1p + k * D_);
    #pragma unroll
    for (int r = 0; r < 4; ++r) {
      float xv = xq[r * D_ + k];
      acc[r][0] += xv * wv.x; acc[r][1] += xv * wv.y;
      acc[r][2] += xv * wv.z; acc[r][3] += xv * wv.w;
    }
  }
  #pragma unroll
  for (int r = 0; r < 4; ++r) red[t][r] = acc[r];
  __syncthreads();
  const int r = t >> 6;
  const int c2 = t & 63;
  f32x4 s = red[c2][r];
  #pragma unroll
  for (int q = 1; q < 4; ++q) {
    f32x4 v = red[c2 + 64 * q][r];
    s[0] += v[0]; s[1] += v[1]; s[2] += v[2]; s[3] += v[3];
  }
  const int fe4 = (c2 & 31) * 4;
  const int row = row0 + r;
  if ((c2 >> 5) == 0) {
    float4 bv = *(const float4*)(b1 + fe4);
    s[0] += bv.x; s[1] += bv.y; s[2] += bv.z; s[3] += bv.w;
    *(f32x4*)(Aq + row * D_ + fe4) = s;
  } else {
    *(f32x4*)(Cq + row * D_ + fe4) = s;
  }
}

// Edge v9.1: r19 verbatim (best, 36.96us) + exp2-folded sigmoid epilogue:
// sigmoid(acc+b2) = rcp(1 + exp2(fma(acc, -log2e, -b2*log2e))), the b2 term
// hoisted per-lane. 5->4 ops per sigmoid (2 trans), shorter dep chain.
// j-quarter, 64 KB f32 LDS (pure-copy swizzled), 2 blocks/CU, no spill.
// MFMA A: row=lane&15 (=j), k=8*(lane>>4)+e. D: col=lane&15 (=h),
// row=(lane>>4)*4+reg. (verified r2-r19)
__global__ __launch_bounds__(512, 4)
void edge_kernel(const float* __restrict__ Aq, const float* __restrict__ Cq,
                 const float* __restrict__ w2, const float* __restrict__ b2,
                 float* __restrict__ out) {
  __shared__ float cs[128 * D_];         // 64 KB f32
  const int t = threadIdx.x;
  const int lane = t & 63;
  const int wid = t >> 6;                // 0..7
  const int b  = blockIdx.x >> 8;
  const int jq = (blockIdx.x >> 6) & 3;  // j quarter
  const int ig = blockIdx.x & 63;
  const int i  = ig * 8 + wid;

  const int jcol = lane & 15;            // j within tile == output h
  const int lgrp = lane >> 4;            // k-group
  const int sw = jcol & 7;

  // ---- stage C quarter f32 (pure copy, swizzled): 4096 units / 512 thr
  {
    const float* cb = Cq + (size_t)(b * S_ + jq * 128) * D_;
    #pragma unroll
    for (int it = 0; it < 8; ++it) {
      int p = t + it * 512;
      int row = p >> 5, u = p & 31;      // 32 x 16B-units per row
      float4 v = *(const float4*)(cb + row * D_ + u * 4);
      *(float4*)(cs + row * D_ + ((u ^ (row & 7)) * 4)) = v;
    }
  }

  // a registers as packed f32x2 (b1 folded in proj) — r9 verbatim
  f32x2 apk[4][4];
  {
    const float* Ai = Aq + (b * S_ + i) * D_ + lgrp * 8;
    #pragma unroll
    for (int ch = 0; ch < 4; ++ch) {
      float4 v0 = *(const float4*)(Ai + ch * 32);
      float4 v1 = *(const float4*)(Ai + ch * 32 + 4);
      apk[ch][0][0] = v0.x; apk[ch][0][1] = v0.y;
      apk[ch][1][0] = v0.z; apk[ch][1][1] = v0.w;
      apk[ch][2][0] = v1.x; apk[ch][2][1] = v1.y;
      apk[ch][3][0] = v1.z; apk[ch][3][1] = v1.w;
    }
  }
  // w2 B-frags (bf16) — r9 verbatim
  bf16x8 w2f[4];
  #pragma unroll
  for (int ch = 0; ch < 4; ++ch) {
    #pragma unroll
    for (int e = 0; e < 8; ++e) {
      float wv = (jcol < H_) ? w2[(ch * 32 + lgrp * 8 + e) * H_ + jcol] : 0.0f;
      w2f[ch][e] = f2bf(wv);
    }
  }
  const float NL2E = -1.4426950408889634f;           // -log2(e)
  const float b2l = (jcol < H_) ? b2[jcol] * NL2E : 0.0f;  // -b2*log2e (neg in NL2E)
  float* outp = out + (((size_t)(b * H_ + (jcol & 7)) * S_ + i) * S_)
                + jq * 128 + lgrp * 4;

  __syncthreads();                       // only barrier

  #pragma unroll 1
  for (int jt = 0; jt < 8; ++jt) {
    const float* bp = cs + (jt * 16 + jcol) * D_;
    f32x4 acc = {0.f, 0.f, 0.f, 0.f};
    #pragma unroll
    for (int ch = 0; ch < 4; ++ch) {
      const int u0 = ch * 8 + lgrp * 2;  // logical 16B-unit (even)
      float4 c0 = *(const float4*)(bp + ((u0 ^ sw) * 4));
      float4 c1 = *(const float4*)(bp + (((u0 + 1) ^ sw) * 4));
      u32x4 hfd;
      f32x2 v;
      v[0] = c0.x; v[1] = c0.y; v += apk[ch][0];
      hfd[0] = cvt_pk_bf16(fmaxf(v[0], 0.f), fmaxf(v[1], 0.f));
      v[0] = c0.z; v[1] = c0.w; v += apk[ch][1];
      hfd[1] = cvt_pk_bf16(fmaxf(v[0], 0.f), fmaxf(v[1], 0.f));
      v[0] = c1.x; v[1] = c1.y; v += apk[ch][2];
      hfd[2] = cvt_pk_bf16(fmaxf(v[0], 0.f), fmaxf(v[1], 0.f));
      v[0] = c1.z; v[1] = c1.w; v += apk[ch][3];
      hfd[3] = cvt_pk_bf16(fmaxf(v[0], 0.f), fmaxf(v[1], 0.f));
      bf16x8 hf = __builtin_bit_cast(bf16x8, hfd);
      acc = __builtin_amdgcn_mfma_f32_16x16x32_bf16(hf, w2f[ch], acc, 0, 0, 0);
    }
    if (jcol < H_) {
      float4 o;
      o.x = __builtin_amdgcn_rcpf(
          1.0f + __builtin_amdgcn_exp2f(fmaf(acc[0], NL2E, b2l)));
      o.y = __builtin_amdgcn_rcpf(
          1.0f + __builtin_amdgcn_exp2f(fmaf(acc[1], NL2E, b2l)));
      o.z = __builtin_amdgcn_rcpf(
          1.0f + __builtin_amdgcn_exp2f(fmaf(acc[2], NL2E, b2l)));
      o.w = __builtin_amdgcn_rcpf(
          1.0f + __builtin_amdgcn_exp2f(fmaf(acc[3], NL2E, b2l)));
      *(float4*)(outp + jt * 16) = o;
    }
  }
}

extern "C" void kernel_launch(void* const* d_in, const int* in_sizes, int n_in,
                              void* d_out, int out_size, void* d_ws, size_t ws_size,
                              hipStream_t stream) {
  const float* x  = (const float*)d_in[0];
  const float* w1 = (const float*)d_in[1];
  const float* b1 = (const float*)d_in[2];
  const float* w2 = (const float*)d_in[3];
  const float* b2 = (const float*)d_in[4];
  float* out = (float*)d_out;
  float* Aq = (float*)d_ws;                 // 2048*128 f32 = 1 MB
  float* Cq = Aq + B_ * S_ * D_;            // +1 MB
  proj_kernel<<<(B_ * S_) / 4, 256, 0, stream>>>(x, w1, b1, Aq, Cq);
  edge_kernel<<<B_ * 4 * 64, 512, 0, stream>>>(Aq, Cq, w2, b2, out);
}